// Round 1
// baseline (3378.220 us; speedup 1.0000x reference)
//
#include <hip/hip_runtime.h>
#include <hip/hip_cooperative_groups.h>

#define HH 2048
#define WW 2048
#define NPX (HH*WW)
#define INFV 1e30f
#define TILE 64
#define NTX 32
#define NTILES 1024
#define LS 68   /* LDS row stride for 66-col halo tile */

namespace cg = cooperative_groups;

// ---------- shared math (pinned rounding so every pass computes identical fr) ----------
__device__ __forceinline__ float sobel_at(const float* __restrict__ g, int y, int x){
  float a00,a01,a02,a10,a12,a20,a21,a22;
  if (y>0 && y<HH-1 && x>0 && x<WW-1){
    const float* p = g + (size_t)(y-1)*WW + x;
    a00=p[-1]; a01=p[0]; a02=p[1];
    p += WW;   a10=p[-1];          a12=p[1];
    p += WW;   a20=p[-1]; a21=p[0]; a22=p[1];
  } else {
    auto at=[&](int yy,int xx)->float{
      return (yy<0||yy>=HH||xx<0||xx>=WW)?0.0f:g[(size_t)yy*WW+xx];
    };
    a00=at(y-1,x-1); a01=at(y-1,x); a02=at(y-1,x+1);
    a10=at(y,  x-1);                a12=at(y,  x+1);
    a20=at(y+1,x-1); a21=at(y+1,x); a22=at(y+1,x+1);
  }
  float gx = __fadd_rn(__fadd_rn(__fsub_rn(a02,a00), __fmul_rn(2.0f,__fsub_rn(a12,a10))), __fsub_rn(a22,a20));
  float gy = __fadd_rn(__fadd_rn(__fsub_rn(a20,a00), __fmul_rn(2.0f,__fsub_rn(a21,a01))), __fsub_rn(a22,a02));
  return sqrtf(__fadd_rn(__fmul_rn(gx,gx),__fmul_rn(gy,gy)));
}

// ---------- gray ----------
__global__ void gray_kernel(const float* __restrict__ img, float* __restrict__ gray){
  const float* R=img; const float* G=img+NPX; const float* B=img+2*(size_t)NPX;
  for (int i=blockIdx.x*blockDim.x+threadIdx.x; i<NPX; i+=gridDim.x*blockDim.x){
    gray[i] = __fadd_rn(__fadd_rn(__fmul_rn(0.2989f,R[i]),__fmul_rn(0.587f,G[i])),__fmul_rn(0.114f,B[i]));
  }
}

// ---------- 3-level radix selection of 4 order statistics ----------
__global__ void hist_l1(const float* __restrict__ gray, unsigned* __restrict__ hist){
  __shared__ unsigned h[4*2048];
  for (int i=threadIdx.x;i<4*2048;i+=blockDim.x) h[i]=0;
  __syncthreads();
  const int rep=(threadIdx.x&3)*2048;
  for (int i=blockIdx.x*blockDim.x+threadIdx.x; i<NPX; i+=gridDim.x*blockDim.x){
    int y=i>>11, x=i&(WW-1);
    unsigned key=__float_as_uint(sobel_at(gray,y,x));
    atomicAdd(&h[rep+(key>>21)],1u);
  }
  __syncthreads();
  for (int i=threadIdx.x;i<2048;i+=blockDim.x){
    unsigned s=h[i]+h[i+2048]+h[i+4096]+h[i+6144];
    if (s) atomicAdd(&hist[i],s);
  }
}

__global__ void hist_l2(const float* __restrict__ gray, const unsigned* __restrict__ sel1,
                        unsigned* __restrict__ hist2){
  __shared__ unsigned h[4*2048];
  __shared__ unsigned sb[4];
  if (threadIdx.x<4) sb[threadIdx.x]=sel1[threadIdx.x];
  for (int i=threadIdx.x;i<4*2048;i+=blockDim.x) h[i]=0;
  __syncthreads();
  for (int i=blockIdx.x*blockDim.x+threadIdx.x; i<NPX; i+=gridDim.x*blockDim.x){
    int y=i>>11, x=i&(WW-1);
    unsigned key=__float_as_uint(sobel_at(gray,y,x));
    unsigned b=key>>21, sub=(key>>10)&0x7FFu;
    #pragma unroll
    for (int k=0;k<4;++k) if (b==sb[k]) atomicAdd(&h[k*2048+sub],1u);
  }
  __syncthreads();
  for (int i=threadIdx.x;i<4*2048;i+=blockDim.x){ unsigned s=h[i]; if (s) atomicAdd(&hist2[i],s); }
}

__global__ void hist_l3(const float* __restrict__ gray, const unsigned* __restrict__ sel1,
                        const unsigned* __restrict__ sel2, unsigned* __restrict__ hist3){
  __shared__ unsigned h[4*1024];
  __shared__ unsigned pf[4];
  if (threadIdx.x<4) pf[threadIdx.x]=(sel1[threadIdx.x]<<11)|sel2[threadIdx.x];
  for (int i=threadIdx.x;i<4*1024;i+=blockDim.x) h[i]=0;
  __syncthreads();
  for (int i=blockIdx.x*blockDim.x+threadIdx.x; i<NPX; i+=gridDim.x*blockDim.x){
    int y=i>>11, x=i&(WW-1);
    unsigned key=__float_as_uint(sobel_at(gray,y,x));
    unsigned p22=key>>10, sub=key&0x3FFu;
    #pragma unroll
    for (int k=0;k<4;++k) if (p22==pf[k]) atomicAdd(&h[k*1024+sub],1u);
  }
  __syncthreads();
  for (int i=threadIdx.x;i<4*1024;i+=blockDim.x){ unsigned s=h[i]; if (s) atomicAdd(&hist3[i],s); }
}

// ranks: floor(0.9825*(n-1))=4120902, floor(0.9925*(n-1))=4162845 (and +1 each)
__global__ void scan_l1(const unsigned* __restrict__ hist, unsigned* __restrict__ sel1,
                        unsigned* __restrict__ rem1){
  __shared__ unsigned part[1024];
  const int t=threadIdx.x;
  unsigned a=hist[2*t], b=hist[2*t+1];
  part[t]=a+b; __syncthreads();
  for (int off=1;off<1024;off<<=1){
    unsigned add=(t>=off)?part[t-off]:0u; __syncthreads();
    part[t]+=add; __syncthreads();
  }
  unsigned before=(t>0)?part[t-1]:0u;
  const unsigned R[4]={4120902u,4120903u,4162845u,4162846u};
  unsigned cum=before;
  #pragma unroll
  for (int i=0;i<4;++i) if (R[i]>=cum && R[i]<cum+a){ sel1[i]=2*t;   rem1[i]=R[i]-cum; }
  cum+=a;
  #pragma unroll
  for (int i=0;i<4;++i) if (R[i]>=cum && R[i]<cum+b){ sel1[i]=2*t+1; rem1[i]=R[i]-cum; }
}

__global__ void scan_l2(const unsigned* __restrict__ hist2, const unsigned* __restrict__ rem1,
                        unsigned* __restrict__ sel2, unsigned* __restrict__ rem2){
  __shared__ unsigned part[1024];
  const int t=threadIdx.x;
  for (int i=0;i<4;++i){
    const unsigned* hh=hist2+i*2048;
    unsigned a=hh[2*t], b=hh[2*t+1];
    part[t]=a+b; __syncthreads();
    for (int off=1;off<1024;off<<=1){
      unsigned add=(t>=off)?part[t-off]:0u; __syncthreads();
      part[t]+=add; __syncthreads();
    }
    unsigned before=(t>0)?part[t-1]:0u;
    unsigned r=rem1[i], cum=before;
    if (r>=cum && r<cum+a){ sel2[i]=2*t;   rem2[i]=r-cum; }
    cum+=a;
    if (r>=cum && r<cum+b){ sel2[i]=2*t+1; rem2[i]=r-cum; }
    __syncthreads();
  }
}

__global__ void scan_l3(const unsigned* __restrict__ hist3, const unsigned* __restrict__ sel1,
                        const unsigned* __restrict__ sel2, const unsigned* __restrict__ rem2,
                        float* __restrict__ scal){
  __shared__ unsigned part[1024];
  __shared__ float vals[4];
  const int t=threadIdx.x;
  for (int i=0;i<4;++i){
    unsigned c=hist3[i*1024+t];
    part[t]=c; __syncthreads();
    for (int off=1;off<1024;off<<=1){
      unsigned add=(t>=off)?part[t-off]:0u; __syncthreads();
      part[t]+=add; __syncthreads();
    }
    unsigned before=(t>0)?part[t-1]:0u;
    unsigned r=rem2[i];
    if (r>=before && r<before+c){
      unsigned key=(sel1[i]<<21)|(sel2[i]<<10)|(unsigned)t;
      vals[i]=__uint_as_float(key);
    }
    __syncthreads();
  }
  if (t==0){
    // f32 index = q*(n-1) lands on x.75 exactly for both quantiles -> weights (0.25, 0.75)
    scal[0]=__fadd_rn(__fmul_rn(vals[0],0.25f),__fmul_rn(vals[1],0.75f));
    scal[1]=__fadd_rn(__fmul_rn(vals[2],0.25f),__fmul_rn(vals[3],0.75f));
  }
}

// ---------- markers -> initial costs ----------
__global__ void init_cost(const float* __restrict__ gray, const float* __restrict__ scal,
                          float* __restrict__ c1, float* __restrict__ c2){
  const float qlo=scal[0], qhi=scal[1];
  for (int i=blockIdx.x*blockDim.x+threadIdx.x; i<NPX; i+=gridDim.x*blockDim.x){
    int y=i>>11, x=i&(WW-1);
    float fr=sobel_at(gray,y,x);
    float g=gray[i];
    bool m1 = (fr<=qlo);
    bool m2 = (!m1) && (fr>=qhi);
    c1[i] = m1 ? g : INFV;
    c2[i] = m2 ? g : INFV;
  }
}

// ---------- cooperative fixed-point solver ----------
#define CELL(JJ) do{                                                        \
    const int j_=(JJ);                                                      \
    const int r_=rg*16+j_;                                                  \
    const int base_=(r_+1)*LS+col+1;                                        \
    float n1=L1[base_-LS], s1=L1[base_+LS], w1=L1[base_-1], e1=L1[base_+1]; \
    float m1v=fminf(fminf(n1,s1),fminf(w1,e1));                             \
    float cd1=fmaxf(m1v,g[j_]);                                             \
    if (cd1<v1[j_]){ v1[j_]=cd1; L1[base_]=cd1; ch=true; }                  \
    float n2=L2[base_-LS], s2=L2[base_+LS], w2=L2[base_-1], e2=L2[base_+1]; \
    float m2v=fminf(fminf(n2,s2),fminf(w2,e2));                             \
    float cd2=fmaxf(m2v,g[j_]);                                             \
    if (cd2<v2[j_]){ v2[j_]=cd2; L2[base_]=cd2; ch=true; }                  \
  }while(0)

__device__ bool relax_tile(int tile, int it,
                           float* __restrict__ c1, float* __restrict__ c2,
                           const float* __restrict__ gray,
                           float* L1, float* L2,
                           int* bflag, int* banyf, int* sneed,
                           int* dr, int* dw)
{
  const int tid=threadIdx.x;
  __syncthreads();            // protect LDS reuse across tiles
  if (tid==0){
    int need=(it==0)?1:0;
    if (!need){
      int ty=tile>>5, tx=tile&31;
      need=__hip_atomic_load(&dr[tile],__ATOMIC_RELAXED,__HIP_MEMORY_SCOPE_AGENT);
      if(!need&&ty>0)  need=__hip_atomic_load(&dr[tile-NTX],__ATOMIC_RELAXED,__HIP_MEMORY_SCOPE_AGENT);
      if(!need&&ty<31) need=__hip_atomic_load(&dr[tile+NTX],__ATOMIC_RELAXED,__HIP_MEMORY_SCOPE_AGENT);
      if(!need&&tx>0)  need=__hip_atomic_load(&dr[tile-1],__ATOMIC_RELAXED,__HIP_MEMORY_SCOPE_AGENT);
      if(!need&&tx<31) need=__hip_atomic_load(&dr[tile+1],__ATOMIC_RELAXED,__HIP_MEMORY_SCOPE_AGENT);
    }
    *sneed=need; *bflag=0; *banyf=0;
  }
  __syncthreads();
  if (!*sneed) return false;

  const int col=tid&63, rg=tid>>6;
  const int ty=tile>>5, tx=tile&31;
  const int by=ty*TILE, bx=tx*TILE;

  float v1[16], v2[16], g[16];
  #pragma unroll
  for (int j=0;j<16;++j){
    const int r=rg*16+j;
    const int gi=(by+r)*WW+bx+col;
    float a=c1[gi], b=c2[gi];
    v1[j]=a; v2[j]=b; g[j]=gray[gi];
    L1[(r+1)*LS+col+1]=a;
    L2[(r+1)*LS+col+1]=b;
  }
  if (rg==0){
    float a=(by>0)?c1[(by-1)*WW+bx+col]:INFV;
    float b=(by>0)?c2[(by-1)*WW+bx+col]:INFV;
    L1[col+1]=a; L2[col+1]=b;
  } else if (rg==1){
    float a=(by+TILE<HH)?c1[(by+TILE)*WW+bx+col]:INFV;
    float b=(by+TILE<HH)?c2[(by+TILE)*WW+bx+col]:INFV;
    L1[65*LS+col+1]=a; L2[65*LS+col+1]=b;
  } else if (rg==2){
    float a=(bx>0)?c1[(by+col)*WW+bx-1]:INFV;
    float b=(bx>0)?c2[(by+col)*WW+bx-1]:INFV;
    L1[(col+1)*LS]=a; L2[(col+1)*LS]=b;
  } else {
    float a=(bx+TILE<WW)?c1[(by+col)*WW+bx+TILE]:INFV;
    float b=(bx+TILE<WW)?c2[(by+col)*WW+bx+TILE]:INFV;
    L1[(col+1)*LS+65]=a; L2[(col+1)*LS+65]=b;
  }
  __syncthreads();

  int liter=0;
  for(;;){
    bool ch=false;
    if ((liter&1)==0){
      #pragma unroll
      for (int jj=0;jj<16;++jj) CELL(jj);
    } else {
      #pragma unroll
      for (int jj=0;jj<16;++jj) CELL(15-jj);
    }
    if (ch){ *bflag=1; *banyf=1; }
    __syncthreads();
    int f=*bflag;
    __syncthreads();
    if (tid==0) *bflag=0;
    ++liter;
    if (!f || liter>=512) break;
  }
  __syncthreads();
  bool bc=((*banyf)!=0);
  if (bc){
    #pragma unroll
    for (int j=0;j<16;++j){
      const int r=rg*16+j;
      const int gi=(by+r)*WW+bx+col;
      c1[gi]=v1[j]; c2[gi]=v2[j];
    }
    if (tid==0) __hip_atomic_store(&dw[tile],1,__ATOMIC_RELAXED,__HIP_MEMORY_SCOPE_AGENT);
  }
  return bc;
}

__global__ void __launch_bounds__(256,4)
ws_solve(float* __restrict__ c1, float* __restrict__ c2, const float* __restrict__ gray,
         int* flags, int* dirty0, int* dirty1)
{
  __shared__ float L1[66*LS];
  __shared__ float L2[66*LS];
  __shared__ int bflag, banyf, sneed;
  cg::grid_group grid = cg::this_grid();
  const int tid=threadIdx.x;
  for (int it=0; it<2048; ++it){
    int* dr=(it&1)?dirty1:dirty0;
    int* dw=(it&1)?dirty0:dirty1;
    bool passch=false;
    for (int tile=blockIdx.x; tile<NTILES; tile+=gridDim.x)
      passch |= relax_tile(tile,it,c1,c2,gray,L1,L2,&bflag,&banyf,&sneed,dr,dw);
    if (tid==0 && passch) atomicOr(&flags[it&1],1);
    __threadfence();
    grid.sync();
    int ch=__hip_atomic_load(&flags[it&1],__ATOMIC_RELAXED,__HIP_MEMORY_SCOPE_AGENT);
    if (blockIdx.x==0 && tid==0)
      __hip_atomic_store(&flags[(it+1)&1],0,__ATOMIC_RELAXED,__HIP_MEMORY_SCOPE_AGENT);
    for (int t2=blockIdx.x*blockDim.x+tid; t2<NTILES; t2+=gridDim.x*blockDim.x)
      __hip_atomic_store(&dr[t2],0,__ATOMIC_RELAXED,__HIP_MEMORY_SCOPE_AGENT);
    __threadfence();
    grid.sync();
    if (!ch) break;
    __threadfence();
  }
}

// ---------- output (c2 lives in d_out; rewrite in place) ----------
__global__ void out_kernel(const float* __restrict__ c1, float* o){
  for (int i=blockIdx.x*blockDim.x+threadIdx.x; i<NPX; i+=gridDim.x*blockDim.x){
    o[i] = (o[i] < c1[i]) ? 1.0f : 0.0f;
  }
}

extern "C" void kernel_launch(void* const* d_in, const int* in_sizes, int n_in,
                              void* d_out, int out_size, void* d_ws, size_t ws_size,
                              hipStream_t stream)
{
  const float* img=(const float*)d_in[0];
  float* out=(float*)d_out;
  char* wsb=(char*)d_ws;
  float* gray=(float*)wsb;
  float* c1  =(float*)(wsb + (size_t)NPX*4);
  unsigned* meta=(unsigned*)(wsb + (size_t)NPX*8);
  float* c2 = out;   // reuse output buffer as c2 scratch (fully rewritten each launch)

  unsigned* hist1=meta;            // 2048
  unsigned* hist2=meta+2048;       // 4*2048
  unsigned* hist3=meta+10240;      // 4*1024
  unsigned* sel1 =meta+14336;
  unsigned* rem1 =meta+14340;
  unsigned* sel2 =meta+14344;
  unsigned* rem2 =meta+14348;
  float*    scal =(float*)(meta+14352);   // 2
  int*      flags=(int*)(meta+14354);     // 2
  int*      dirty0=(int*)(meta+14356);    // 1024
  int*      dirty1=(int*)(meta+15380);    // 1024  -> total 16404 u32

  hipMemsetAsync(meta, 0, 16404*sizeof(unsigned), stream);
  hipLaunchKernelGGL(gray_kernel, dim3(4096), dim3(256), 0, stream, img, gray);
  hipLaunchKernelGGL(hist_l1, dim3(1024), dim3(256), 0, stream, gray, hist1);
  hipLaunchKernelGGL(scan_l1, dim3(1), dim3(1024), 0, stream, hist1, sel1, rem1);
  hipLaunchKernelGGL(hist_l2, dim3(1024), dim3(256), 0, stream, gray, sel1, hist2);
  hipLaunchKernelGGL(scan_l2, dim3(1), dim3(1024), 0, stream, hist2, rem1, sel2, rem2);
  hipLaunchKernelGGL(hist_l3, dim3(1024), dim3(256), 0, stream, gray, sel1, sel2, hist3);
  hipLaunchKernelGGL(scan_l3, dim3(1), dim3(1024), 0, stream, hist3, sel1, sel2, rem2, scal);
  hipLaunchKernelGGL(init_cost, dim3(4096), dim3(256), 0, stream, gray, scal, c1, c2);

  int dev=0; (void)hipGetDevice(&dev);
  int cus=0; (void)hipDeviceGetAttribute(&cus, hipDeviceAttributeMultiprocessorCount, dev);
  int nb=0;  (void)hipOccupancyMaxActiveBlocksPerMultiprocessor(&nb, ws_solve, 256, 0);
  if (cus<=0) cus=256;
  if (nb<=0) nb=1;
  long long gmax=(long long)nb*(long long)cus;
  int grid=(int)((gmax<NTILES)?gmax:NTILES);
  void* args[]={ (void*)&c1,(void*)&c2,(void*)&gray,(void*)&flags,(void*)&dirty0,(void*)&dirty1 };
  (void)hipLaunchCooperativeKernel(ws_solve, dim3(grid), dim3(256), args, 0, stream);

  hipLaunchKernelGGL(out_kernel, dim3(4096), dim3(256), 0, stream, c1, out);
}